// Round 8
// baseline (110.859 us; speedup 1.0000x reference)
//
#include <hip/hip_runtime.h>
#include <math.h>

#define Bb 4
#define Cc 256
#define Hh 128
#define Ww 128
#define HW (Hh * Ww)
#define Kk 9
#define PLANE (Bb * Kk * HW)   // one full D tensor (589,824 floats)

typedef float f32x4 __attribute__((ext_vector_type(4)));

// ---------------------------------------------------------------------------
// Kernel 1: Dp[cg][b][k][p] = sum_{c in group cg} x[b][c][p] * w[c*9 + k]
// Granule test: block = (batch, channel-group of 64, 1024-pixel tile)
//   -> each per-channel read is 4 KB contiguous (4x R6's 1 KB granule).
// grid = 4*4*16 = 256 blocks x 512 threads. Thread t: pixel-quad (t&255),
// half = t>>8 picks even/odd channel of a pair (32 pairs = 64 channels).
// LDS pair-reduce, then coalesced f32x4 stores to this group's partial
// plane (no atomics, no zeroing, fully deterministic).
// ---------------------------------------------------------------------------
__global__ __launch_bounds__(512) void proj_kernel(const float* __restrict__ x,
                                                   const float* __restrict__ w,
                                                   float* __restrict__ Dp) {
    const int tid  = threadIdx.x;
    const int pxq  = tid & 255;            // f32x4 index within 1024-px tile
    const int half = tid >> 8;             // 0/1, wave-uniform
    const int bid  = blockIdx.x;           // 0..255
    const int b    = bid >> 6;             // batch
    const int cg   = (bid >> 4) & 3;       // channel-group (64 ch)
    const int tile = bid & 15;             // 1024-px tile
    const int pb   = tile << 10;           // tile pixel base

    const int c0 = cg * 64 + __builtin_amdgcn_readfirstlane(half);
    const float* __restrict__ wp = w + c0 * Kk;
    const float* __restrict__ xp = x + (size_t)(b * Cc + c0) * HW + pb + pxq * 4;

    f32x4 acc[Kk];
#pragma unroll
    for (int k = 0; k < Kk; ++k) acc[k] = (f32x4)(0.f);

#pragma unroll 8
    for (int ci = 0; ci < 32; ++ci) {       // channel = c0 + 2*ci
        const f32x4 xv = *reinterpret_cast<const f32x4*>(xp + (size_t)(2 * ci) * HW);
#pragma unroll
        for (int k = 0; k < Kk; ++k) {
            const float wk = wp[ci * 2 * Kk + k];
            acc[k] = __builtin_elementwise_fma(xv, (f32x4)(wk), acc[k]);
        }
    }

    // Pair-reduce the two channel-halves in LDS, coalesced store to Dp[cg].
    __shared__ f32x4 red[256][Kk];          // 36,864 B
    if (half == 1) {
#pragma unroll
        for (int k = 0; k < Kk; ++k) red[pxq][k] = acc[k];
    }
    __syncthreads();
    if (half == 0) {
        float* __restrict__ dst = Dp + (size_t)cg * PLANE;
#pragma unroll
        for (int k = 0; k < Kk; ++k) {
            const f32x4 v = acc[k] + red[pxq][k];
            *reinterpret_cast<f32x4*>(dst + (size_t)(b * Kk + k) * HW + pb + pxq * 4) = v;
        }
    }
}

// ---------------------------------------------------------------------------
// Kernel 1b: Dsum[i] = Dp[0][i] + Dp[1][i] + Dp[2][i] + Dp[3][i]  (f32x4)
// 576 blocks x 256 threads, one f32x4 per thread.
// ---------------------------------------------------------------------------
__global__ __launch_bounds__(256) void combine_kernel(const float* __restrict__ Dp,
                                                      float* __restrict__ Dsum) {
    const int i = (blockIdx.x * 256 + threadIdx.x) * 4;   // < PLANE
    const f32x4 a = *reinterpret_cast<const f32x4*>(Dp + 0 * (size_t)PLANE + i);
    const f32x4 b = *reinterpret_cast<const f32x4*>(Dp + 1 * (size_t)PLANE + i);
    const f32x4 c = *reinterpret_cast<const f32x4*>(Dp + 2 * (size_t)PLANE + i);
    const f32x4 d = *reinterpret_cast<const f32x4*>(Dp + 3 * (size_t)PLANE + i);
    *reinterpret_cast<f32x4*>(Dsum + i) = (a + b) + (c + d);
}

// ---------------------------------------------------------------------------
// Kernel 2: bilinear-sample the 9 projected planes, reduce, sigmoid.
// (unchanged from R6)
// ---------------------------------------------------------------------------
__global__ __launch_bounds__(512) void sample_kernel(const float* __restrict__ off,
                                                     const float* __restrict__ D,
                                                     const float* __restrict__ bias,
                                                     float* __restrict__ out) {
    const int tid   = threadIdx.x;         // 0..511
    const int px    = tid & 127;
    const int g     = tid >> 7;            // 0..3, wave-uniform
    const int bid   = blockIdx.x;          // 0..511
    const int b     = bid >> 7;            // 128 blocks per batch image
    const int pbase = (bid & 127) << 7;    // 128 pixels per block
    const int p     = pbase + px;
    const int h     = p >> 7;
    const int w_    = p & (Ww - 1);

    const float* __restrict__ offb = off + (size_t)b * (2 * Kk) * HW + p;
    const float* __restrict__ Db   = D + (size_t)b * Kk * HW;

    float s = 0.f;

#define TAP(K)                                                                 \
    do {                                                                       \
        constexpr int kk = (K);                                                \
        constexpr int ky = kk / 3, kx = kk % 3;                                \
        const float dy = offb[(size_t)(2 * kk) * HW];                          \
        const float dx = offb[(size_t)(2 * kk + 1) * HW];                      \
        const float y  = (float)(h - 1 + ky) + dy;                             \
        const float xq = (float)(w_ - 1 + kx) + dx;                            \
        const float y0f = floorf(y);                                           \
        const float x0f = floorf(xq);                                          \
        const float wy  = y - y0f;                                             \
        const float wx  = xq - x0f;                                            \
        const int y0 = (int)y0f;                                               \
        const int x0 = (int)x0f;                                               \
        const float* __restrict__ Dk = Db + kk * HW;                           \
        {                                                                      \
            const int yy = y0, xx = x0;                                        \
            const bool valid = (yy >= 0) & (yy < Hh) & (xx >= 0) & (xx < Ww);  \
            const int yi = min(max(yy, 0), Hh - 1);                            \
            const int xi = min(max(xx, 0), Ww - 1);                            \
            const float v = Dk[yi * Ww + xi];                                  \
            s += valid ? (1.f - wy) * (1.f - wx) * v : 0.f;                    \
        }                                                                      \
        {                                                                      \
            const int yy = y0, xx = x0 + 1;                                    \
            const bool valid = (yy >= 0) & (yy < Hh) & (xx >= 0) & (xx < Ww);  \
            const int yi = min(max(yy, 0), Hh - 1);                            \
            const int xi = min(max(xx, 0), Ww - 1);                            \
            const float v = Dk[yi * Ww + xi];                                  \
            s += valid ? (1.f - wy) * wx * v : 0.f;                            \
        }                                                                      \
        {                                                                      \
            const int yy = y0 + 1, xx = x0;                                    \
            const bool valid = (yy >= 0) & (yy < Hh) & (xx >= 0) & (xx < Ww);  \
            const int yi = min(max(yy, 0), Hh - 1);                            \
            const int xi = min(max(xx, 0), Ww - 1);                            \
            const float v = Dk[yi * Ww + xi];                                  \
            s += valid ? wy * (1.f - wx) * v : 0.f;                            \
        }                                                                      \
        {                                                                      \
            const int yy = y0 + 1, xx = x0 + 1;                                \
            const bool valid = (yy >= 0) & (yy < Hh) & (xx >= 0) & (xx < Ww);  \
            const int yi = min(max(yy, 0), Hh - 1);                            \
            const int xi = min(max(xx, 0), Ww - 1);                            \
            const float v = Dk[yi * Ww + xi];                                  \
            s += valid ? wy * wx * v : 0.f;                                    \
        }                                                                      \
    } while (0)

    if (g == 0) {
        TAP(0); TAP(4); TAP(8);
    } else if (g == 1) {
        TAP(1); TAP(5);
    } else if (g == 2) {
        TAP(2); TAP(6);
    } else {
        TAP(3); TAP(7);
    }
#undef TAP

    __shared__ float part[4][128];
    part[g][px] = s;
    __syncthreads();

    if (tid < 128) {
        const float t = part[0][px] + part[1][px] + part[2][px] + part[3][px] + bias[0];
        out[(b << 14) + pbase + px] = 1.f / (1.f + expf(-t));
    }
}

extern "C" void kernel_launch(void* const* d_in, const int* in_sizes, int n_in,
                              void* d_out, int out_size, void* d_ws, size_t ws_size,
                              hipStream_t stream) {
    const float* x    = (const float*)d_in[0];  // [4,256,128,128]
    const float* off  = (const float*)d_in[1];  // [4,18,128,128]
    const float* w    = (const float*)d_in[2];  // [1,256,3,3]
    const float* bias = (const float*)d_in[3];  // [1]
    float* out        = (float*)d_out;          // [4,1,128,128]

    float* Dp   = (float*)d_ws;                 // 4 partial planes (9 MB)
    float* Dsum = Dp + 4 * (size_t)PLANE;       // combined plane (2.25 MB)

    proj_kernel<<<256, 512, 0, stream>>>(x, w, Dp);
    combine_kernel<<<PLANE / 1024, 256, 0, stream>>>(Dp, Dsum);
    sample_kernel<<<512, 512, 0, stream>>>(off, Dsum, bias, out);
}

// Round 9
// 108.791 us; speedup vs baseline: 1.0190x; 1.0190x over previous
//
#include <hip/hip_runtime.h>
#include <math.h>

#define Bb 4
#define Cc 256
#define Hh 128
#define Ww 128
#define HW (Hh * Ww)
#define Kk 9

typedef float f32x4 __attribute__((ext_vector_type(4)));

// ---------------------------------------------------------------------------
// Kernel 1: D[b][k][p] = sum_c x[b][c][p] * w[c*9 + k]   (verbatim R6 winner)
// grid = 256 blocks x 1024 threads (16 waves) -> 1 block/CU, 16 waves/CU.
// Wave wv owns channels [wv*16, wv*16+16); each lane owns 4 consecutive
// pixels via one dwordx4 load (1 KB contiguous per wave-instruction).
// Two-phase LDS reduction (16 -> 8 -> sum of 8). LDS = 72 KB (1 block/CU).
// ---------------------------------------------------------------------------
__global__ __launch_bounds__(1024, 4) void proj_kernel(const float* __restrict__ x,
                                                       const float* __restrict__ w,
                                                       float* __restrict__ D) {
    const int tid   = threadIdx.x;
    const int lane  = tid & 63;
    const int wv    = tid >> 6;            // 0..15
    const int bid   = blockIdx.x;          // 0..255
    const int b     = bid >> 6;            // 64 blocks per batch image
    const int pbase = (bid & 63) << 8;     // 256 pixels per block
    const int p4    = pbase + lane * 4;    // this lane's first pixel

    const int cu = __builtin_amdgcn_readfirstlane(wv);
    const float* __restrict__ wp = w + cu * 16 * Kk;
    const float* __restrict__ xp = x + (size_t)(b * Cc + cu * 16) * HW + p4;

    f32x4 acc[Kk];
#pragma unroll
    for (int k = 0; k < Kk; ++k) acc[k] = (f32x4)(0.f);

#pragma unroll 4
    for (int ci = 0; ci < 16; ++ci) {
        const f32x4 xv = *reinterpret_cast<const f32x4*>(xp + (size_t)ci * HW);
#pragma unroll
        for (int k = 0; k < Kk; ++k) {
            const float wk = wp[ci * Kk + k];
            acc[k] = __builtin_elementwise_fma(xv, (f32x4)(wk), acc[k]);
        }
    }

    __shared__ f32x4 red[8][64][Kk];       // 73,728 B
    if (wv < 8) {
#pragma unroll
        for (int k = 0; k < Kk; ++k) red[wv][lane][k] = acc[k];
    }
    __syncthreads();
    if (wv >= 8) {
#pragma unroll
        for (int k = 0; k < Kk; ++k) red[wv - 8][lane][k] += acc[k];
    }
    __syncthreads();

    const float* __restrict__ redf = (const float*)red;
    for (int idx = tid; idx < 256 * Kk; idx += 1024) {
        const int k  = idx >> 8;
        const int px = idx & 255;
        const int base = (px >> 2) * (Kk * 4) + k * 4 + (px & 3);
        float s = 0.f;
#pragma unroll
        for (int g = 0; g < 8; ++g) s += redf[g * (64 * Kk * 4) + base];
        D[(b * Kk + k) * HW + pbase + px] = s;
    }
}

// ---------------------------------------------------------------------------
// Kernel 2: bilinear-sample via LDS-staged row window.
// grid = 512 blocks x 512 threads. Block = one output row (b, h0).
// Stage sm[k][r][x] = D[b][k][h0-4+r][x] for r=0..9 (zeros out of range),
// coalesced 512B runs. Tap-group g = tid>>7 handles taps {g, g+4} (+8 if
// g==0). In-window taps (|y0-h0|<=4: ~99.9%) read corners from LDS; rare
// tail lanes take the exact global-gather fallback (identical math).
// ---------------------------------------------------------------------------
__global__ __launch_bounds__(512) void sample_kernel(const float* __restrict__ off,
                                                     const float* __restrict__ D,
                                                     const float* __restrict__ bias,
                                                     float* __restrict__ out) {
    const int tid  = threadIdx.x;          // 0..511
    const int px   = tid & 127;
    const int g    = tid >> 7;             // 0..3, wave-uniform
    const int bid  = blockIdx.x;           // 0..511
    const int b    = bid >> 7;             // batch
    const int h0   = bid & 127;            // output row
    const int p    = (h0 << 7) + px;       // pixel index within image
    const int hm4  = h0 - 4;

    const float* __restrict__ offb = off + (size_t)b * (2 * Kk) * HW + p;
    const float* __restrict__ Db   = D + (size_t)b * Kk * HW;

    // ---- stage the 10-row window for all 9 taps ----
    __shared__ float sm[Kk][10][128];      // 46,080 B
#pragma unroll
    for (int k = 0; k < Kk; ++k) {
        const float* __restrict__ Dk = Db + k * HW;
        for (int j = tid; j < 1280; j += 512) {
            const int r  = j >> 7;
            const int xc = j & 127;
            const int yi = hm4 + r;
            sm[k][r][xc] = (yi >= 0 && yi <= Hh - 1) ? Dk[yi * Ww + xc] : 0.f;
        }
    }
    __syncthreads();

    float s = 0.f;

#define TAP(K)                                                                 \
    do {                                                                       \
        constexpr int kk = (K);                                                \
        constexpr int ky = kk / 3, kx = kk % 3;                                \
        const float dy = offb[(size_t)(2 * kk) * HW];                          \
        const float dx = offb[(size_t)(2 * kk + 1) * HW];                      \
        const float y  = (float)(h0 - 1 + ky) + dy;                            \
        const float xq = (float)(px - 1 + kx) + dx;                            \
        const float y0f = floorf(y);                                           \
        const float x0f = floorf(xq);                                          \
        const float wy  = y - y0f;                                             \
        const float wx  = xq - x0f;                                            \
        const int y0 = (int)y0f;                                               \
        const int x0 = (int)x0f;                                               \
        const int yoff = y0 - hm4;                                             \
        const bool v0x = (y0 >= 0) & (y0 <= Hh - 1);                           \
        const bool v1x = (y0 + 1 >= 0) & (y0 + 1 <= Hh - 1);                   \
        const bool c0v = (x0 >= 0) & (x0 <= Ww - 1);                           \
        const bool c1v = (x0 + 1 >= 0) & (x0 + 1 <= Ww - 1);                   \
        const int xi0 = min(max(x0, 0), Ww - 1);                               \
        const int xi1 = min(max(x0 + 1, 0), Ww - 1);                           \
        if (yoff >= 0 && yoff <= 8) {                                          \
            const float* __restrict__ r0 = sm[kk][yoff];                       \
            const float* __restrict__ r1 = sm[kk][yoff + 1];                   \
            const float v00 = r0[xi0], v01 = r0[xi1];                          \
            const float v10 = r1[xi0], v11 = r1[xi1];                          \
            s += (v0x & c0v) ? (1.f - wy) * (1.f - wx) * v00 : 0.f;            \
            s += (v0x & c1v) ? (1.f - wy) * wx * v01 : 0.f;                    \
            s += (v1x & c0v) ? wy * (1.f - wx) * v10 : 0.f;                    \
            s += (v1x & c1v) ? wy * wx * v11 : 0.f;                            \
        } else {                                                               \
            const float* __restrict__ Dk = Db + kk * HW;                       \
            const int yi0 = min(max(y0, 0), Hh - 1);                           \
            const int yi1 = min(max(y0 + 1, 0), Hh - 1);                       \
            const float v00 = Dk[yi0 * Ww + xi0], v01 = Dk[yi0 * Ww + xi1];    \
            const float v10 = Dk[yi1 * Ww + xi0], v11 = Dk[yi1 * Ww + xi1];    \
            s += (v0x & c0v) ? (1.f - wy) * (1.f - wx) * v00 : 0.f;            \
            s += (v0x & c1v) ? (1.f - wy) * wx * v01 : 0.f;                    \
            s += (v1x & c0v) ? wy * (1.f - wx) * v10 : 0.f;                    \
            s += (v1x & c1v) ? wy * wx * v11 : 0.f;                            \
        }                                                                      \
    } while (0)

    if (g == 0) {
        TAP(0); TAP(4); TAP(8);
    } else if (g == 1) {
        TAP(1); TAP(5);
    } else if (g == 2) {
        TAP(2); TAP(6);
    } else {
        TAP(3); TAP(7);
    }
#undef TAP

    __shared__ float part[4][128];
    part[g][px] = s;
    __syncthreads();

    if (tid < 128) {
        const float t = part[0][px] + part[1][px] + part[2][px] + part[3][px] + bias[0];
        out[(b << 14) + (h0 << 7) + px] = 1.f / (1.f + expf(-t));
    }
}

extern "C" void kernel_launch(void* const* d_in, const int* in_sizes, int n_in,
                              void* d_out, int out_size, void* d_ws, size_t ws_size,
                              hipStream_t stream) {
    const float* x    = (const float*)d_in[0];  // [4,256,128,128]
    const float* off  = (const float*)d_in[1];  // [4,18,128,128]
    const float* w    = (const float*)d_in[2];  // [1,256,3,3]
    const float* bias = (const float*)d_in[3];  // [1]
    float* out        = (float*)d_out;          // [4,1,128,128]

    float* D = (float*)d_ws;  // [4][9][16384] f32 = 2.25 MB scratch

    proj_kernel<<<256, 1024, 0, stream>>>(x, w, D);
    sample_kernel<<<512, 512, 0, stream>>>(off, D, bias, out);
}